// Round 2
// baseline (3704.015 us; speedup 1.0000x reference)
//
#include <hip/hip_runtime.h>
#include <math.h>

namespace {
constexpr int kNodes = 50000;
constexpr int kEdges = 1600000;
constexpr int kD     = 128;   // node/edge feature dim
constexpr int kHid   = 256;   // MLP hidden dim
constexpr int kKin   = 256;   // 2*kD, GEMM1 K
constexpr float kEps = 1e-5f;

constexpr int MT = 64;        // nodes per block (M tile)
constexpr int S  = 260;       // LDS row stride in floats (256 + 4 pad; 1040B = 65*16 keeps float4 alignment)
}

// ---------------------------------------------------------------------------
// Scatter-add: agg[dst[e]] += edge_attr[e]   (atomic f32, agent scope)
// 32 threads per edge, each owns a float4 (4 dims). kEdges % 8 == 0.
// ---------------------------------------------------------------------------
__global__ __launch_bounds__(256) void scatter_add_kernel(
    const float* __restrict__ edge_attr,
    const int*   __restrict__ dst,
    float*       __restrict__ agg)
{
    const int t = threadIdx.x;
    const int e = blockIdx.x * 8 + (t >> 5);
    const int d = (t & 31) * 4;
    const int n = dst[e];
    const float4 v = *reinterpret_cast<const float4*>(edge_attr + (size_t)e * kD + d);
    float* p = agg + (size_t)n * kD + d;
    __hip_atomic_fetch_add(p + 0, v.x, __ATOMIC_RELAXED, __HIP_MEMORY_SCOPE_AGENT);
    __hip_atomic_fetch_add(p + 1, v.y, __ATOMIC_RELAXED, __HIP_MEMORY_SCOPE_AGENT);
    __hip_atomic_fetch_add(p + 2, v.z, __ATOMIC_RELAXED, __HIP_MEMORY_SCOPE_AGENT);
    __hip_atomic_fetch_add(p + 3, v.w, __ATOMIC_RELAXED, __HIP_MEMORY_SCOPE_AGENT);
}

// ---------------------------------------------------------------------------
// Fused MLP + LayerNorm + residual.
// Block: 256 threads = 8 groups of 32 lanes; each group owns 8 node rows.
//  Phase A: stage concat([x, agg]) tile [64][256] into LDS (stride 260).
//           Then each thread grabs its residual float4s into registers.
//  Phase B: h1 = silu(in @ W1 + b1) -> back into same LDS buffer.
//           Thread tile: 8 nodes x (4 cols @ lane*4, 4 cols @ 128+lane*4).
//           k unrolled by 4 with ds_read_b128; h1 written as 2x ds_write_b128
//           at stride 4 floats (conflict-free).
//  Phase C: h2 = h1 @ W2 + b2; LN over 128 cols via shfl_xor across the
//           32 lanes of the group; out = x + LN(h2)*gamma + beta.
// ---------------------------------------------------------------------------
__global__ __launch_bounds__(256) void mlp_fused_kernel(
    const float* __restrict__ x,
    const float* __restrict__ agg,
    const float* __restrict__ W1,
    const float* __restrict__ b1,
    const float* __restrict__ W2,
    const float* __restrict__ b2,
    const float* __restrict__ gamma,
    const float* __restrict__ beta,
    float*       __restrict__ out)
{
    __shared__ float lds[MT * S];   // 66,560 B -> 2 blocks/CU (LDS-limited occupancy)
    const int t     = threadIdx.x;
    const int node0 = blockIdx.x * MT;
    const int lane  = t & 31;
    const int m0    = (t >> 5) * 8;     // this group's first node row

    // ---- Phase A: load x|agg tile ----
    {
        const int cg = lane * 4;        // float4 column within 128
        const int r0 = t >> 5;
        #pragma unroll
        for (int r = r0; r < MT; r += 8) {
            const int node = node0 + r;
            float4 vx = make_float4(0.f, 0.f, 0.f, 0.f);
            float4 va = make_float4(0.f, 0.f, 0.f, 0.f);
            if (node < kNodes) {
                vx = *reinterpret_cast<const float4*>(x   + (size_t)node * kD + cg);
                va = *reinterpret_cast<const float4*>(agg + (size_t)node * kD + cg);
            }
            *reinterpret_cast<float4*>(&lds[r * S + cg])      = vx;
            *reinterpret_cast<float4*>(&lds[r * S + kD + cg]) = va;
        }
    }
    __syncthreads();

    // ---- Grab residual x for this thread's output columns (before h1 overwrite) ----
    const int c2 = lane * 4;            // 4 output cols in [0,128)
    float4 xres[8];
    #pragma unroll
    for (int i = 0; i < 8; ++i)
        xres[i] = *reinterpret_cast<const float4*>(&lds[(m0 + i) * S + c2]);

    // ---- Phase B: GEMM1 + bias + SiLU ----
    {
        const int c0a = lane * 4;       // hidden cols 0..127
        const int c0b = 128 + lane * 4; // hidden cols 128..255
        float acc[8][8];                // [i][0..3] -> c0a.., [i][4..7] -> c0b..
        #pragma unroll
        for (int i = 0; i < 8; ++i)
            #pragma unroll
            for (int j = 0; j < 8; ++j) acc[i][j] = 0.f;

        for (int k = 0; k < kKin; k += 4) {
            float4 v4[8];
            #pragma unroll
            for (int i = 0; i < 8; ++i)
                v4[i] = *reinterpret_cast<const float4*>(&lds[(m0 + i) * S + k]);
            #pragma unroll
            for (int kk = 0; kk < 4; ++kk) {
                const float4 wa = *reinterpret_cast<const float4*>(W1 + (size_t)(k + kk) * kHid + c0a);
                const float4 wb = *reinterpret_cast<const float4*>(W1 + (size_t)(k + kk) * kHid + c0b);
                #pragma unroll
                for (int i = 0; i < 8; ++i) {
                    const float v = (&v4[i].x)[kk];
                    acc[i][0] += v * wa.x; acc[i][1] += v * wa.y;
                    acc[i][2] += v * wa.z; acc[i][3] += v * wa.w;
                    acc[i][4] += v * wb.x; acc[i][5] += v * wb.y;
                    acc[i][6] += v * wb.z; acc[i][7] += v * wb.w;
                }
            }
        }
        __syncthreads();   // everyone done reading the input tile

        const float4 b1a = *reinterpret_cast<const float4*>(b1 + c0a);
        const float4 b1b = *reinterpret_cast<const float4*>(b1 + c0b);
        #pragma unroll
        for (int i = 0; i < 8; ++i) {
            float4 ha, hb;
            ha.x = acc[i][0] + b1a.x; ha.y = acc[i][1] + b1a.y;
            ha.z = acc[i][2] + b1a.z; ha.w = acc[i][3] + b1a.w;
            hb.x = acc[i][4] + b1b.x; hb.y = acc[i][5] + b1b.y;
            hb.z = acc[i][6] + b1b.z; hb.w = acc[i][7] + b1b.w;
            ha.x = ha.x / (1.f + __expf(-ha.x));
            ha.y = ha.y / (1.f + __expf(-ha.y));
            ha.z = ha.z / (1.f + __expf(-ha.z));
            ha.w = ha.w / (1.f + __expf(-ha.w));
            hb.x = hb.x / (1.f + __expf(-hb.x));
            hb.y = hb.y / (1.f + __expf(-hb.y));
            hb.z = hb.z / (1.f + __expf(-hb.z));
            hb.w = hb.w / (1.f + __expf(-hb.w));
            *reinterpret_cast<float4*>(&lds[(m0 + i) * S + c0a]) = ha;  // conflict-free b128
            *reinterpret_cast<float4*>(&lds[(m0 + i) * S + c0b]) = hb;
        }
    }
    __syncthreads();

    // ---- Phase C: GEMM2 + bias + LayerNorm + residual ----
    {
        float acc2[8][4];
        #pragma unroll
        for (int i = 0; i < 8; ++i)
            #pragma unroll
            for (int j = 0; j < 4; ++j) acc2[i][j] = 0.f;

        for (int k = 0; k < kHid; k += 4) {
            float4 v4[8];
            #pragma unroll
            for (int i = 0; i < 8; ++i)
                v4[i] = *reinterpret_cast<const float4*>(&lds[(m0 + i) * S + k]);
            #pragma unroll
            for (int kk = 0; kk < 4; ++kk) {
                const float4 w = *reinterpret_cast<const float4*>(W2 + (size_t)(k + kk) * kD + c2);
                #pragma unroll
                for (int i = 0; i < 8; ++i) {
                    const float v = (&v4[i].x)[kk];
                    acc2[i][0] += v * w.x; acc2[i][1] += v * w.y;
                    acc2[i][2] += v * w.z; acc2[i][3] += v * w.w;
                }
            }
        }

        const float4 b2v = *reinterpret_cast<const float4*>(b2    + c2);
        const float4 gv  = *reinterpret_cast<const float4*>(gamma + c2);
        const float4 bev = *reinterpret_cast<const float4*>(beta  + c2);

        #pragma unroll
        for (int i = 0; i < 8; ++i) {
            const float h0 = acc2[i][0] + b2v.x;
            const float h1 = acc2[i][1] + b2v.y;
            const float h2 = acc2[i][2] + b2v.z;
            const float h3 = acc2[i][3] + b2v.w;
            float s  = h0 + h1 + h2 + h3;
            float ss = h0*h0 + h1*h1 + h2*h2 + h3*h3;
            // reduce across the 32 lanes of this node group (offsets stay in-half)
            #pragma unroll
            for (int off = 16; off >= 1; off >>= 1) {
                s  += __shfl_xor(s,  off, 64);
                ss += __shfl_xor(ss, off, 64);
            }
            const float mu   = s * (1.f / kD);
            const float var  = ss * (1.f / kD) - mu * mu;
            const float rstd = rsqrtf(var + kEps);

            const int node = node0 + m0 + i;
            if (node < kNodes) {
                float4 o;
                o.x = xres[i].x + (h0 - mu) * rstd * gv.x + bev.x;
                o.y = xres[i].y + (h1 - mu) * rstd * gv.y + bev.y;
                o.z = xres[i].z + (h2 - mu) * rstd * gv.z + bev.z;
                o.w = xres[i].w + (h3 - mu) * rstd * gv.w + bev.w;
                *reinterpret_cast<float4*>(out + (size_t)node * kD + c2) = o;
            }
        }
    }
}

// ---------------------------------------------------------------------------
extern "C" void kernel_launch(void* const* d_in, const int* in_sizes, int n_in,
                              void* d_out, int out_size, void* d_ws, size_t ws_size,
                              hipStream_t stream)
{
    const float* x     = (const float*)d_in[0];
    const int*   eidx  = (const int*)  d_in[1];   // [2, kEdges]
    const float* eattr = (const float*)d_in[2];
    const float* W1    = (const float*)d_in[3];
    const float* b1    = (const float*)d_in[4];
    const float* W2    = (const float*)d_in[5];
    const float* b2    = (const float*)d_in[6];
    const float* gamma = (const float*)d_in[7];
    const float* beta  = (const float*)d_in[8];
    float* out = (float*)d_out;
    float* agg = (float*)d_ws;                    // [kNodes, kD] scratch

    // ws is re-poisoned 0xAA before every launch -> zero it ourselves
    hipMemsetAsync(agg, 0, (size_t)kNodes * kD * sizeof(float), stream);

    const int* dst = eidx + kEdges;               // edge_index[1] = destinations
    scatter_add_kernel<<<kEdges / 8, 256, 0, stream>>>(eattr, dst, agg);

    const int nblk = (kNodes + MT - 1) / MT;      // 782
    mlp_fused_kernel<<<nblk, 256, 0, stream>>>(x, agg, W1, b1, W2, b2,
                                               gamma, beta, out);
}